// Round 5
// baseline (8733.811 us; speedup 1.0000x reference)
//
#include <hip/hip_runtime.h>
#include <math.h>
#include <stdint.h>

// Problem constants
#define DD 500
#define BB 512
#define NW 3072        // padded N: gi 0..1499, gh 1500..2999, pad..3071
#define NSTRIPS 96     // n-strips of 32 (3072/32)
#define MSTRIPS 16     // m-strips of 32 (512/32)
#define KSTEPS  96     // ksteps of 16 (K=1536: [Ah|Al|Ah] x [Wh|Wh|Wl])
#define NELEM (BB*DD)
#define NBLK 256       // 256 blocks x 256 thr: co-residency guaranteed by
                       // capacity (even 1 block/CU covers the grid)

typedef _Float16 f16;
typedef _Float16 f16x8 __attribute__((ext_vector_type(8)));
typedef float    f32x16 __attribute__((ext_vector_type(16)));

// Fragment-order layout (Ap and Wp):
//   elem(strip, kstep, ln, j) at ((strip*KSTEPS + kstep)*64 + ln)*8 + j
//   maps to row = strip*32 + (ln&31), k = kstep*16 + (ln>>5)*8 + j
//   == mfma_f32_32x32x16_f16 A/B operand layout.

// ---------------------------------------------------------------------------
// Wp (frag order) from W_ih/W_hh. k-blocks of 512: [Wh | Wh | Wl]; bk>=500->0
// ---------------------------------------------------------------------------
__global__ __launch_bounds__(256) void conv_w(const float* __restrict__ Wih,
                                              const float* __restrict__ Whh,
                                              f16* __restrict__ Wp)
{
    int p = blockIdx.x * 256 + threadIdx.x;
    const int ln = p & 63; p >>= 6;
    const int kstep = p % KSTEPS;
    const int strip = p / KSTEPS;              // 0..95
    const int n = strip * 32 + (ln & 31);
    const int kb0 = kstep * 16 + (ln >> 5) * 8;
    const int blk = kb0 >> 9, bk0 = kb0 & 511;
    const float* src = 0;
    if (n < 1500)      src = Wih + (size_t)n * DD;
    else if (n < 3000) src = Whh + (size_t)(n - 1500) * DD;
    f16 out[8];
    #pragma unroll
    for (int j = 0; j < 8; ++j) {
        const int bk = bk0 + j;
        float v = (src && bk < DD) ? src[bk] : 0.f;
        f16 hi = (f16)v;
        out[j] = (blk == 2) ? (f16)(v - (float)hi) : hi;
    }
    *(uint4*)(Wp + ((size_t)(strip * KSTEPS + kstep) * 64 + ln) * 8) = *(uint4*)out;
}

// ---------------------------------------------------------------------------
// Ap (frag order) from initial state. k-blocks: [Ah | Al | Ah]
// ---------------------------------------------------------------------------
__global__ __launch_bounds__(256) void conv_a(const float* __restrict__ S,
                                              f16* __restrict__ Ap)
{
    int p = blockIdx.x * 256 + threadIdx.x;
    const int ln = p & 63; p >>= 6;
    const int kstep = p % KSTEPS;
    const int strip = p / KSTEPS;              // 0..15
    const int b = strip * 32 + (ln & 31);
    const int kb0 = kstep * 16 + (ln >> 5) * 8;
    const int blk = kb0 >> 9, bk0 = kb0 & 511;
    f16 out[8];
    #pragma unroll
    for (int j = 0; j < 8; ++j) {
        const int bk = bk0 + j;
        float v = (bk < DD) ? S[(size_t)b * DD + bk] : 0.f;
        f16 hi = (f16)v;
        out[j] = (blk == 1) ? (f16)(v - (float)hi) : hi;
    }
    *(uint4*)(Ap + ((size_t)(strip * KSTEPS + kstep) * 64 + ln) * 8) = *(uint4*)out;
}

// ---------------------------------------------------------------------------
// device-scope grid barrier (generation counter). bar[0]=cnt, bar[1]=gen.
// All NBLK blocks are resident (capacity argument above), so spinning is safe.
// ---------------------------------------------------------------------------
__device__ __forceinline__ void grid_barrier(int* bar)
{
    __syncthreads();
    if (threadIdx.x == 0) {
        __threadfence();   // release: publish this block's global writes (wb L2)
        int g = __hip_atomic_load(bar + 1, __ATOMIC_RELAXED, __HIP_MEMORY_SCOPE_AGENT);
        int old = __hip_atomic_fetch_add(bar, 1, __ATOMIC_ACQ_REL, __HIP_MEMORY_SCOPE_AGENT);
        if (old == NBLK - 1) {
            __hip_atomic_store(bar, 0, __ATOMIC_RELAXED, __HIP_MEMORY_SCOPE_AGENT);
            __hip_atomic_store(bar + 1, g + 1, __ATOMIC_RELEASE, __HIP_MEMORY_SCOPE_AGENT);
        } else {
            while (__hip_atomic_load(bar + 1, __ATOMIC_ACQUIRE, __HIP_MEMORY_SCOPE_AGENT) == g)
                __builtin_amdgcn_s_sleep(2);
        }
        __threadfence();   // acquire side: invalidate L1/L2 before block reads
    }
    __syncthreads();
}

// ---------------------------------------------------------------------------
// Persistent kernel (plain launch, 256 blocks): 64x (GEMM -> bar -> EW -> bar).
// bid = bmt*32 + bnt*2 + kh; blocks sharing (bnt,kh) differ by 32 = 0 mod 8
// -> same XCD -> shared Wp column-tile stays L2-local.
// GEMM: block tile 64m x 192n, K-half 768; 4 waves, wave-tile 32m x 96n:
// 1 LDS A-frag feeds 3 B-streams (global->register ring, depth 8 ksteps).
// ---------------------------------------------------------------------------
__global__ __launch_bounds__(256, 2) void gru_persist(
    f16* __restrict__ Ap, const f16* __restrict__ Wp,
    float* __restrict__ C0, float* __restrict__ C1,
    const float* __restrict__ bih, const float* __restrict__ bhh,
    float* __restrict__ h, const float* __restrict__ bc,
    const int* __restrict__ rec, float* __restrict__ slots, int* bar)
{
    const int bid = blockIdx.x;
    const int tid = threadIdx.x;
    const int wv = tid >> 6, ln = tid & 63;
    const int rec0 = rec[0];
    const float thr = bc[0] * (float)NELEM;

    const int bmt = bid >> 5;          // 0..7  M-tile (64 rows)
    const int g   = bid & 31;
    const int bnt = g >> 1;            // 0..15 N-tile (192 cols = 6 strips)
    const int kh  = g & 1;             // K half
    float* __restrict__ Cmy = kh ? C1 : C0;
    const int ks0 = kh * 48;

    const int wm = wv & 1;             // m-strip within tile (32 rows)
    const int wn = wv >> 1;            // n-strip triple (96 cols)

    __shared__ f16 As[2][4096];        // 2 x 8 KB: [(mf*4+ksl)*64 + l]*8
    __shared__ float red[4];
    __shared__ int bcast;

    // loop-invariant addresses ------------------------------------------------
    int a_ld[2]; const f16* a_gp[2];
    #pragma unroll
    for (int j = 0; j < 2; ++j) {
        const int s = j * 256 + tid;       // 512 piece-lane slots
        const int p = s >> 6, l = s & 63;
        const int mf = p >> 2, ksl = p & 3;
        a_ld[j] = ((mf * 4 + ksl) * 64 + l) * 8;
        const int ms = bmt * 2 + mf;
        a_gp[j] = Ap + ((size_t)(ms * KSTEPS + ks0 + ksl) * 64 + l) * 8;
    }
    const int sbase = bnt * 6 + wn * 3;    // first of this wave's 3 n-strips
    const f16* Bp[3];
    #pragma unroll
    for (int j = 0; j < 3; ++j)
        Bp[j] = Wp + ((size_t)((sbase + j) * KSTEPS + ks0) * 64 + ln) * 8;

    bool done = false;
    for (int t = 0; t < 64; ++t) {
        if (t >= rec0 || done) break;

        // ---------------- GEMM phase ----------------
        const bool skipg = (t == 0) && (bnt >= 8);   // cols>=1536: gh/pad only
        if (!skipg) {
            f32x16 acc0 = {}, acc1 = {}, acc2 = {};
            uint4 br0[2][4], br1[2][4], br2[2][4];
            #pragma unroll
            for (int i = 0; i < 8; ++i) {
                br0[i >> 2][i & 3] = *(const uint4*)(Bp[0] + (size_t)i * 512);
                br1[i >> 2][i & 3] = *(const uint4*)(Bp[1] + (size_t)i * 512);
                br2[i >> 2][i & 3] = *(const uint4*)(Bp[2] + (size_t)i * 512);
            }
            uint4 sreg[2];
            #pragma unroll
            for (int j = 0; j < 2; ++j) sreg[j] = *(const uint4*)(a_gp[j]);
            #pragma unroll
            for (int j = 0; j < 2; ++j) *(uint4*)&As[0][a_ld[j]] = sreg[j];
            __syncthreads();

            for (int c = 0; c < 12; ++c) {            // 12 chunks x 4 ksteps
                const int cur = c & 1;
                if (c < 11) {
                    #pragma unroll
                    for (int j = 0; j < 2; ++j)
                        sreg[j] = *(const uint4*)(a_gp[j] + (size_t)(c + 1) * 2048);
                }
                #pragma unroll
                for (int ksl = 0; ksl < 4; ++ksl) {
                    f16x8 af = *(const f16x8*)&As[cur][((wm * 4 + ksl) * 64 + ln) * 8];
                    acc0 = __builtin_amdgcn_mfma_f32_32x32x16_f16(af, *(f16x8*)&br0[cur][ksl], acc0, 0, 0, 0);
                    acc1 = __builtin_amdgcn_mfma_f32_32x32x16_f16(af, *(f16x8*)&br1[cur][ksl], acc1, 0, 0, 0);
                    acc2 = __builtin_amdgcn_mfma_f32_32x32x16_f16(af, *(f16x8*)&br2[cur][ksl], acc2, 0, 0, 0);
                    const int ks = c * 4 + ksl;
                    if (ks + 8 < 48) {                 // refill ring slot
                        br0[cur][ksl] = *(const uint4*)(Bp[0] + (size_t)(ks + 8) * 512);
                        br1[cur][ksl] = *(const uint4*)(Bp[1] + (size_t)(ks + 8) * 512);
                        br2[cur][ksl] = *(const uint4*)(Bp[2] + (size_t)(ks + 8) * 512);
                    }
                }
                if (c < 11) {
                    #pragma unroll
                    for (int j = 0; j < 2; ++j) *(uint4*)&As[cur ^ 1][a_ld[j]] = sreg[j];
                    __syncthreads();
                }
            }
            // epilogue: C/D layout col=lane&31, row=(r&3)+8*(r>>2)+4*(lane>>5)
            const int col = sbase * 32 + (ln & 31);
            const int rb  = bmt * 64 + wm * 32 + 4 * (ln >> 5);
            #pragma unroll
            for (int r = 0; r < 16; ++r) {
                const int row = rb + (r & 3) + 8 * (r >> 2);
                Cmy[(size_t)row * NW + col]      = acc0[r];
                Cmy[(size_t)row * NW + col + 32] = acc1[r];
                Cmy[(size_t)row * NW + col + 64] = acc2[r];
            }
        }

        grid_barrier(bar);

        // ---------------- EW phase ----------------
        float lsum = 0.f;
        for (int e = bid * 256 + tid; e < NELEM; e += NBLK * 256) {
            const unsigned b = (unsigned)e / 500u;
            const int d = e - (int)b * 500;
            const float* Cb0 = C0 + (size_t)b * NW;
            const float* Cb1 = C1 + (size_t)b * NW;
            float ir  = Cb0[d]        + Cb1[d]        + bih[d];
            float iz  = Cb0[500 + d]  + Cb1[500 + d]  + bih[500 + d];
            float inn = Cb0[1000 + d] + Cb1[1000 + d] + bih[1000 + d];
            float hr = bhh[d];
            float hz = bhh[500 + d];
            float hn = bhh[1000 + d];
            float hp = 0.0f;
            if (t > 0) {
                hr += Cb0[1500 + d] + Cb1[1500 + d];
                hz += Cb0[2000 + d] + Cb1[2000 + d];
                hn += Cb0[2500 + d] + Cb1[2500 + d];
                hp = h[e];
            }
            float r = 1.0f / (1.0f + expf(-(ir + hr)));
            float z = 1.0f / (1.0f + expf(-(iz + hz)));
            float n = tanhf(inn + r * hn);
            float hnew = (1.0f - z) * n + z * hp;
            h[e] = hnew;
            lsum += hnew;
            // refresh Ap (frag order): k = d (hi), 512+d (lo), 1024+d (hi)
            const int ms = (int)b >> 5, lm = (int)b & 31;
            f16 hi = (f16)hnew;
            f16 lo = (f16)(hnew - (float)hi);
            const int kstep = d >> 4, half = (d >> 3) & 1, j = d & 7;
            const size_t base = ((size_t)(ms * KSTEPS + kstep) * 64 + half * 32 + lm) * 8 + j;
            Ap[base]            = hi;   // k-block 0
            Ap[base + 32 * 512] = lo;   // k-block 1 (+32 ksteps)
            Ap[base + 64 * 512] = hi;   // k-block 2 (+64 ksteps)
        }
        // block-reduce partial sum -> slots[t]
        float v = lsum;
        #pragma unroll
        for (int off = 32; off > 0; off >>= 1) v += __shfl_down(v, off, 64);
        if (ln == 0) red[wv] = v;
        __syncthreads();
        if (tid == 0) atomicAdd(&slots[t], red[0] + red[1] + red[2] + red[3]);

        grid_barrier(bar);

        if (tid == 0) bcast = (slots[t] > thr) ? 1 : 0;
        __syncthreads();
        done = (bcast != 0);
    }
}

extern "C" void kernel_launch(void* const* d_in, const int* in_sizes, int n_in,
                              void* d_out, int out_size, void* d_ws, size_t ws_size,
                              hipStream_t stream)
{
    const float* state = (const float*)d_in[0];
    const float* Wih   = (const float*)d_in[1];
    const float* Whh   = (const float*)d_in[2];
    const float* bih   = (const float*)d_in[3];
    const float* bhh   = (const float*)d_in[4];
    const float* bc    = (const float*)d_in[5];
    const int*   rec   = (const int*)d_in[6];

    char* ws = (char*)d_ws;
    int*   bar   = (int*)ws;                            // 8 B (cnt, gen)
    float* slots = (float*)(ws + 256);                  // 64 floats
    f16*   Ap    = (f16*)(ws + 1024);                   // 1.5 MB
    f16*   Wp    = (f16*)(ws + 1024 + (size_t)MSTRIPS * KSTEPS * 512 * 2);
    float* C0    = (float*)(ws + 1024 + (size_t)MSTRIPS * KSTEPS * 512 * 2
                                      + (size_t)NSTRIPS * KSTEPS * 512 * 2);
    float* C1    = C0 + (size_t)BB * NW;
    float* out   = (float*)d_out;

    hipMemsetAsync(ws, 0, 1024, stream);   // bar + slots
    // rec==0 robustness: output = state if no iteration runs
    hipMemcpyAsync(out, state, (size_t)NELEM * sizeof(float),
                   hipMemcpyDeviceToDevice, stream);

    conv_w<<<dim3(NSTRIPS * KSTEPS * 64 / 256), 256, 0, stream>>>(Wih, Whh, Wp);
    conv_a<<<dim3(MSTRIPS * KSTEPS * 64 / 256), 256, 0, stream>>>(state, Ap);

    gru_persist<<<dim3(NBLK), dim3(256), 0, stream>>>(
        Ap, Wp, C0, C1, bih, bhh, out, bc, rec, slots, bar);
}

// Round 6
// 3913.324 us; speedup vs baseline: 2.2318x; 2.2318x over previous
//
#include <hip/hip_runtime.h>
#include <math.h>
#include <stdint.h>

// Problem constants
#define DD 500
#define BB 512
#define KSTEPS 96      // K=1536 (fp16 split [hi|lo|hi]) in 16-wide ksteps
#define NELEM (BB*DD)
#define NBLK 256       // 16 bmt x 16 ng; 256 blocks <= 256 CUs: all resident

typedef _Float16 f16;
typedef _Float16 f16x8 __attribute__((ext_vector_type(8)));
typedef float    f32x16 __attribute__((ext_vector_type(16)));

// Wp gate-major fragment layout: strip s = g*16 + ng (g=0..5: i_r,i_z,i_n,
// h_r,h_z,h_n; dim d = (s%16)*32 + (ln&31), padded 500->512).
// elem(s, ks, ln, j) at ((s*96+ks)*64+ln)*8+j ; k' = ks*16+(ln>>5)*8+j;
// kb = k'>>9: 0 -> W hi, 1 -> W hi, 2 -> W lo. (A side: 0 hi, 1 lo, 2 hi.)

__global__ __launch_bounds__(256) void conv_w(const float* __restrict__ Wih,
                                              const float* __restrict__ Whh,
                                              f16* __restrict__ Wp)
{
    int p = blockIdx.x * 256 + threadIdx.x;    // (s, ks, ln)
    const int ln = p & 63; p >>= 6;
    const int ks = p % KSTEPS;
    const int s  = p / KSTEPS;                 // 0..95
    const int np = s * 32 + (ln & 31);
    const int g  = np >> 9;                    // gate 0..5
    const int d  = np & 511;
    const int k0 = ks * 16 + ((ln >> 5) << 3);
    const int kb = k0 >> 9, kl = k0 & 511;
    f16 out[8];
    #pragma unroll
    for (int j = 0; j < 8; ++j) {
        const int kk = kl + j;
        float v = 0.f;
        if (d < DD && kk < DD)
            v = (g < 3) ? Wih[(size_t)(g * DD + d) * DD + kk]
                        : Whh[(size_t)((g - 3) * DD + d) * DD + kk];
        f16 hi = (f16)v;
        out[j] = (kb == 2) ? (f16)(v - (float)hi) : hi;
    }
    *(uint4*)(Wp + ((size_t)(s * KSTEPS + ks) * 64 + ln) * 8) = *(uint4*)out;
}

// coherent (agent-scope, cache-bypassing) helpers --------------------------
__device__ __forceinline__ void loadA8(const float* p, int kl0, int alimit,
                                       uint64_t* dst)
{
    #pragma unroll
    for (int q = 0; q < 4; ++q) {
        dst[q] = (kl0 + 2 * q < alimit)
            ? __hip_atomic_load((const uint64_t*)(p + 2 * q),
                                __ATOMIC_RELAXED, __HIP_MEMORY_SCOPE_AGENT)
            : 0ull;
    }
}

__device__ __forceinline__ f16x8 cvt_split(const uint64_t* u, int kb)
{
    f16x8 r;
    #pragma unroll
    for (int q = 0; q < 4; ++q) {
        union { uint64_t u64; float f[2]; } x; x.u64 = u[q];
        f16 h0 = (f16)x.f[0], h1 = (f16)x.f[1];
        if (kb == 1) { h0 = (f16)(x.f[0] - (float)h0);
                       h1 = (f16)(x.f[1] - (float)h1); }
        r[2 * q]     = h0;
        r[2 * q + 1] = h1;
    }
    return r;
}

// ---------------------------------------------------------------------------
// Persistent kernel. Block (bmt, ng): rows [bmt*32,+32), gate-dims
// [ng*32,+32). Per iter: GEMM M=32 N=192(6 strips) K=1536, 4 waves split K
// (24 ksteps each) -> LDS partials -> in-block EW -> h ping-pong via
// agent-atomic stores -> counter barrier (release add + relaxed poll; no
// fences => L2 never invalidated; Wp stays cached).
// ---------------------------------------------------------------------------
__global__ __launch_bounds__(256, 1) void gru_persist(
    const float* __restrict__ state, const f16* __restrict__ Wp,
    float* __restrict__ H0, float* __restrict__ H1,
    const float* __restrict__ bih, const float* __restrict__ bhh,
    float* __restrict__ hout, const float* __restrict__ bc,
    const int* __restrict__ rec, float* __restrict__ slots, unsigned* cnt)
{
    const int bid = blockIdx.x;
    const int bmt = bid >> 4;          // 0..15 row group
    const int ng  = bid & 15;          // 0..15 gate-dim group (same ng -> same XCD)
    const int tid = threadIdx.x, wv = tid >> 6, ln = tid & 63;
    const int rec0 = rec[0];
    const float thr = bc[0] * (float)NELEM;

    __shared__ float part[4][6][32][36];   // 108 KB, stride 36: conflict-free
    __shared__ float red[4];
    __shared__ int dflag;

    const int rowA = bmt * 32 + (ln & 31);
    const int ks0  = wv * 24;              // this wave's K range
    // EW mapping: thread -> (row er, 4 gate-dims at ec0)
    const int er  = tid >> 3;
    const int ec0 = (tid & 7) * 4;
    const int gb  = bmt * 32 + er;         // batch row for EW

    #define KL0(i) ((((ks0 + (i)) & 31) << 4) + ((ln >> 5) << 3))
    #define KB(i)  ((ks0 + (i)) >> 5)

    for (int t = 0; t < 64 && t < rec0; ++t) {
        const float* Asrc  = (t == 0) ? state : ((t & 1) ? H1 : H0);
        const int astride  = (t == 0) ? 500 : 512;
        const int alimit   = (t == 0) ? 500 : 512;
        float* Hn          = (t & 1) ? H0 : H1;

        // ---------------- GEMM (K split across waves) ----------------
        f32x16 acc[6];
        #pragma unroll
        for (int g = 0; g < 6; ++g) acc[g] = (f32x16){};

        const float* Arow = Asrc + (size_t)rowA * astride;
        uint64_t Ar[8][4];
        uint4    Br[4][6];
        #pragma unroll
        for (int i = 0; i < 8; ++i) loadA8(Arow + KL0(i), KL0(i), alimit, Ar[i]);
        #pragma unroll
        for (int i = 0; i < 4; ++i)
            #pragma unroll
            for (int g = 0; g < 6; ++g)
                Br[i][g] = *(const uint4*)(Wp +
                    ((size_t)((g * 16 + ng) * KSTEPS + ks0 + i) * 64 + ln) * 8);

        #pragma unroll
        for (int i = 0; i < 24; ++i) {
            f16x8 af = cvt_split(Ar[i & 7], KB(i));
            #pragma unroll
            for (int g = 0; g < 6; ++g) {
                f16x8 bf = *(f16x8*)&Br[i & 3][g];
                acc[g] = __builtin_amdgcn_mfma_f32_32x32x16_f16(af, bf, acc[g], 0, 0, 0);
            }
            if (i + 8 < 24) loadA8(Arow + KL0(i + 8), KL0(i + 8), alimit, Ar[(i + 8) & 7]);
            if (i + 4 < 24) {
                #pragma unroll
                for (int g = 0; g < 6; ++g)
                    Br[(i + 4) & 3][g] = *(const uint4*)(Wp +
                        ((size_t)((g * 16 + ng) * KSTEPS + ks0 + i + 4) * 64 + ln) * 8);
            }
        }

        // write per-wave partials to LDS (C/D: col=ln&31, row=(r&3)+8*(r>>2)+4*(ln>>5))
        __syncthreads();   // safe reuse of part[] across iterations
        const int ccol = ln & 31;
        #pragma unroll
        for (int g = 0; g < 6; ++g)
            #pragma unroll
            for (int r = 0; r < 16; ++r) {
                const int crow = (r & 3) + 8 * (r >> 2) + 4 * (ln >> 5);
                part[wv][g][crow][ccol] = acc[g][r];
            }
        __syncthreads();

        // ---------------- EW (fused, in-block) ----------------
        float lsum = 0.f;
        float hn4[4];
        #pragma unroll
        for (int q = 0; q < 4; ++q) hn4[q] = 0.f;
        {
            float c[6];
            #pragma unroll
            for (int g = 0; g < 6; ++g) {
                float4 p0 = *(const float4*)&part[0][g][er][ec0];
                float4 p1 = *(const float4*)&part[1][g][er][ec0];
                float4 p2 = *(const float4*)&part[2][g][er][ec0];
                float4 p3 = *(const float4*)&part[3][g][er][ec0];
                // accumulate per q below; store sums in registers
                ((float4*)&part[0][g][er][ec0], 0);  // no-op
                float4 s4 = make_float4(p0.x + p1.x + p2.x + p3.x,
                                        p0.y + p1.y + p2.y + p3.y,
                                        p0.z + p1.z + p2.z + p3.z,
                                        p0.w + p1.w + p2.w + p3.w);
                // stash into c via per-q loop below
                #pragma unroll
                for (int q = 0; q < 4; ++q) {
                    float cv = (q == 0) ? s4.x : (q == 1) ? s4.y : (q == 2) ? s4.z : s4.w;
                    // process on the last gate pass
                    part[wv][g][0][0] += 0.f;  // keep compiler honest (no-op)
                    if (g == 0) hn4[q] = 0.f;
                    c[g] = cv;  // note: c[] overwritten per q below; restructure:
                }
                (void)c;
            }
        }
        // restructured clean EW loop (per element):
        #pragma unroll
        for (int q = 0; q < 4; ++q) {
            const int dl = ec0 + q;
            const int d  = ng * 32 + dl;
            float cg[6];
            #pragma unroll
            for (int g = 0; g < 6; ++g)
                cg[g] = part[0][g][er][dl] + part[1][g][er][dl]
                      + part[2][g][er][dl] + part[3][g][er][dl];
            float hnew = 0.f;
            if (d < DD) {
                float ir  = cg[0] + bih[d];
                float iz  = cg[1] + bih[500 + d];
                float inn = cg[2] + bih[1000 + d];
                float hr = bhh[d], hz = bhh[500 + d], hnn = bhh[1000 + d];
                float hp = 0.f;
                if (t > 0) {           // t=0: true h_prev=0, gh = bias only
                    hr += cg[3]; hz += cg[4]; hnn += cg[5];
                    hp = hout[(size_t)gb * DD + d];
                }
                float r = 1.0f / (1.0f + expf(-(ir + hr)));
                float z = 1.0f / (1.0f + expf(-(iz + hz)));
                float n = tanhf(inn + r * hnn);
                hnew = (1.0f - z) * n + z * hp;
                hout[(size_t)gb * DD + d] = hnew;   // block-local: plain store
                lsum += hnew;
            }
            hn4[q] = hnew;
        }
        // coherent ping-pong store (write-through to L3; pad dims store 0)
        {
            float* dst = Hn + (size_t)gb * 512 + ng * 32 + ec0;
            union { float f[2]; uint64_t u; } p0, p1;
            p0.f[0] = hn4[0]; p0.f[1] = hn4[1];
            p1.f[0] = hn4[2]; p1.f[1] = hn4[3];
            __hip_atomic_store((uint64_t*)dst,       p0.u, __ATOMIC_RELAXED, __HIP_MEMORY_SCOPE_AGENT);
            __hip_atomic_store((uint64_t*)(dst + 2), p1.u, __ATOMIC_RELAXED, __HIP_MEMORY_SCOPE_AGENT);
        }

        // ---------------- mean + counter barrier ----------------
        float v = lsum;
        #pragma unroll
        for (int off = 32; off > 0; off >>= 1) v += __shfl_down(v, off, 64);
        if (ln == 0) red[wv] = v;
        __syncthreads();
        if (tid == 0) {
            float s = red[0] + red[1] + red[2] + red[3];
            __hip_atomic_fetch_add(&slots[t], s, __ATOMIC_RELAXED, __HIP_MEMORY_SCOPE_AGENT);
            // release: drains the sc stores above before the increment lands
            __hip_atomic_fetch_add(cnt, 1u, __ATOMIC_RELEASE, __HIP_MEMORY_SCOPE_AGENT);
            const unsigned tgt = (unsigned)(t + 1) * NBLK;
            while (__hip_atomic_load(cnt, __ATOMIC_RELAXED, __HIP_MEMORY_SCOPE_AGENT) < tgt)
                __builtin_amdgcn_s_sleep(8);
            float st = __hip_atomic_load(&slots[t], __ATOMIC_RELAXED, __HIP_MEMORY_SCOPE_AGENT);
            dflag = (st > thr) ? 1 : 0;
        }
        __syncthreads();
        if (dflag) break;
    }
    #undef KL0
    #undef KB
}

extern "C" void kernel_launch(void* const* d_in, const int* in_sizes, int n_in,
                              void* d_out, int out_size, void* d_ws, size_t ws_size,
                              hipStream_t stream)
{
    const float* state = (const float*)d_in[0];
    const float* Wih   = (const float*)d_in[1];
    const float* Whh   = (const float*)d_in[2];
    const float* bih   = (const float*)d_in[3];
    const float* bhh   = (const float*)d_in[4];
    const float* bc    = (const float*)d_in[5];
    const int*   rec   = (const int*)d_in[6];

    char* ws = (char*)d_ws;
    unsigned* cnt  = (unsigned*)ws;                       // 4 B
    float* slots   = (float*)(ws + 256);                  // 64 floats
    float* H0      = (float*)(ws + 4096);                 // 512x512 fp32 (1 MB)
    float* H1      = H0 + 512 * 512;
    f16*   Wp      = (f16*)(ws + 4096 + 2u * 512 * 512 * 4);  // 9.4 MB frag-order
    float* out     = (float*)d_out;

    hipMemsetAsync(ws, 0, 1024, stream);   // cnt + slots
    // rec==0 robustness: output = state if no iteration runs
    hipMemcpyAsync(out, state, (size_t)NELEM * sizeof(float),
                   hipMemcpyDeviceToDevice, stream);

    conv_w<<<dim3(96 * KSTEPS * 64 / 256), 256, 0, stream>>>(Wih, Whh, Wp);

    gru_persist<<<dim3(NBLK), dim3(256), 0, stream>>>(
        state, Wp, H0, H1, bih, bhh, out, bc, rec, slots, cnt);
}

// Round 7
// 3162.516 us; speedup vs baseline: 2.7617x; 1.2374x over previous
//
#include <hip/hip_runtime.h>
#include <math.h>
#include <stdint.h>

// Problem constants
#define DD 500
#define BB 512
#define KSTEPS 96      // K=1536 (fp16 split [hi|lo|hi]) in 16-wide ksteps
#define NELEM (BB*DD)
#define NBLK 256       // 16 bmt x 16 ng; 256 blocks <= 256 CUs: all resident

typedef _Float16 f16;
typedef _Float16 f16x8 __attribute__((ext_vector_type(8)));
typedef float    f32x16 __attribute__((ext_vector_type(16)));

// Wp gate-major fragment layout (verified round 6): strip s = g*16 + ng,
// col c=ln&31 -> dim d = ng*32 + c. elem(s,ks,ln,j) at ((s*96+ks)*64+ln)*8+j;
// k = ks*16+(ln>>5)*8+j; kb=k>>9: 0,1 -> W hi, 2 -> W lo. (A: 0 hi, 1 lo, 2 hi)

__global__ __launch_bounds__(256) void conv_w(const float* __restrict__ Wih,
                                              const float* __restrict__ Whh,
                                              f16* __restrict__ Wp)
{
    int p = blockIdx.x * 256 + threadIdx.x;    // (s, ks, ln)
    const int ln = p & 63; p >>= 6;
    const int ks = p % KSTEPS;
    const int s  = p / KSTEPS;                 // 0..95
    const int np = s * 32 + (ln & 31);
    const int g  = np >> 9;                    // gate 0..5
    const int d  = np & 511;
    const int k0 = ks * 16 + ((ln >> 5) << 3);
    const int kb = k0 >> 9, kl = k0 & 511;
    f16 out[8];
    #pragma unroll
    for (int j = 0; j < 8; ++j) {
        const int kk = kl + j;
        float v = 0.f;
        if (d < DD && kk < DD)
            v = (g < 3) ? Wih[(size_t)(g * DD + d) * DD + kk]
                        : Whh[(size_t)((g - 3) * DD + d) * DD + kk];
        f16 hi = (f16)v;
        out[j] = (kb == 2) ? (f16)(v - (float)hi) : hi;
    }
    *(uint4*)(Wp + ((size_t)(s * KSTEPS + ks) * 64 + ln) * 8) = *(uint4*)out;
}

__device__ __forceinline__ uint32_t pack_hl(float x) {
    f16 hi = (f16)x;
    f16 lo = (f16)(x - (float)hi);
    union { f16 h; uint16_t u; } a, b;
    a.h = hi; b.h = lo;
    return (uint32_t)a.u | ((uint32_t)b.u << 16);
}

// ---------------------------------------------------------------------------
// Persistent kernel. Block (bmt, ng): rows [bmt*32,+32), gate-dims
// [ng*32,+32). Per iter: bulk-stage h (packed u32, atomic u64 loads) -> LDS
// Ahi/Alo -> GEMM M=32 N=192 K=1536, 4 waves split K (24 ksteps) with B
// register-ring from cached L2 -> partials to LDS -> fused EW -> packed h
// atomic store -> counter barrier (release add + relaxed poll; L2 never
// invalidated, Wp stays cached).
// ---------------------------------------------------------------------------
__global__ __launch_bounds__(256, 1) void gru_persist(
    const float* __restrict__ state, const f16* __restrict__ Wp,
    uint32_t* __restrict__ Hp0, uint32_t* __restrict__ Hp1,
    const float* __restrict__ bih, const float* __restrict__ bhh,
    float* __restrict__ hout, const float* __restrict__ bc,
    const int* __restrict__ rec, float* __restrict__ slots, unsigned* cnt)
{
    // LDS: A pool (Ahi[32][520] | Alo[32][520], 66560 B) doubles as part
    // storage for waves 0-1 after GEMM; poolP holds waves 2-3 partials.
    __shared__ unsigned char poolA[66560];
    __shared__ unsigned char poolP[50688];
    __shared__ float red[4];
    __shared__ int dflag;

    const int bid = blockIdx.x;
    const int bmt = bid >> 4;          // row group   (same ng -> same XCD)
    const int ng  = bid & 15;          // gate-dim group
    const int tid = threadIdx.x, wv = tid >> 6, ln = tid & 63;
    const int rec0 = rec[0];
    const float thr = bc[0] * (float)NELEM;

    f16* Ah = (f16*)poolA;
    f16* Al = (f16*)(poolA + 33280);
    uint32_t* AhW = (uint32_t*)poolA;
    uint32_t* AlW = (uint32_t*)(poolA + 33280);
    float* part01 = (float*)poolA;
    float* part23 = (float*)poolP;

    const int ks0 = wv * 24;           // this wave's 24 ksteps
    const f16* Bp[6];
    #pragma unroll
    for (int g = 0; g < 6; ++g)
        Bp[g] = Wp + ((size_t)((g * 16 + ng) * KSTEPS + ks0) * 64 + ln) * 8;
    const int arow = (ln & 31) * 520 + ((ln >> 5) << 3);

    const int er = tid >> 3, ec0 = (tid & 7) << 2;   // EW: row er, 4 dims
    const int gb = bmt * 32 + er;

    for (int t = 0; t < 64 && t < rec0; ++t) {
        // ---------------- stage A into LDS ----------------
        if (t == 0) {
            const int dl = tid << 1;
            #pragma unroll 4
            for (int i = 0; i < 32; ++i) {
                float x0 = 0.f, x1 = 0.f;
                if (dl < DD) {   // dl even => dl+1 <= 499 whenever dl < 500
                    float2 v = *(const float2*)(state + (size_t)(bmt * 32 + i) * DD + dl);
                    x0 = v.x; x1 = v.y;
                }
                uint32_t p0 = pack_hl(x0), p1 = pack_hl(x1);
                AhW[i * 260 + tid] = (p0 & 0xffffu) | (p1 << 16);
                AlW[i * 260 + tid] = (p0 >> 16) | (p1 & 0xffff0000u);
            }
        } else {
            const uint64_t* Hs = (const uint64_t*)((t & 1) ? Hp0 : Hp1);
            uint64_t tmp[32];
            #pragma unroll
            for (int i = 0; i < 32; ++i)   // bulk-issued: independent loads
                tmp[i] = __hip_atomic_load(Hs + (size_t)(bmt * 32 + i) * 256 + tid,
                                           __ATOMIC_RELAXED, __HIP_MEMORY_SCOPE_AGENT);
            #pragma unroll
            for (int i = 0; i < 32; ++i) {
                const uint32_t a = (uint32_t)tmp[i], b = (uint32_t)(tmp[i] >> 32);
                AhW[i * 260 + tid] = (a & 0xffffu) | (b << 16);
                AlW[i * 260 + tid] = (a >> 16) | (b & 0xffff0000u);
            }
        }
        __syncthreads();

        // ---------------- GEMM ----------------
        f32x16 acc[6];
        #pragma unroll
        for (int g = 0; g < 6; ++g)
            #pragma unroll
            for (int r = 0; r < 16; ++r) acc[g][r] = 0.f;

        uint4 Br[4][6];
        #pragma unroll
        for (int i = 0; i < 4; ++i)
            #pragma unroll
            for (int g = 0; g < 6; ++g)
                Br[i][g] = *(const uint4*)(Bp[g] + (size_t)i * 512);

        #pragma unroll
        for (int i = 0; i < 24; ++i) {
            const int s = ks0 + i, kb = s >> 5, sl = s & 31;
            const f16* ap = (kb == 1) ? Al : Ah;
            f16x8 af = *(const f16x8*)(ap + arow + sl * 16);
            #pragma unroll
            for (int g = 0; g < 6; ++g)
                acc[g] = __builtin_amdgcn_mfma_f32_32x32x16_f16(
                             af, *(f16x8*)&Br[i & 3][g], acc[g], 0, 0, 0);
            if (i + 4 < 24) {
                #pragma unroll
                for (int g = 0; g < 6; ++g)
                    Br[(i + 4) & 3][g] = *(const uint4*)(Bp[g] + (size_t)(i + 4) * 512);
            }
        }

        __syncthreads();   // all A-frag reads done: A region reusable as part01
        {
            float* pb = (wv < 2) ? part01 : part23;
            const int w2 = wv & 1, ccol = ln & 31, rbase = 4 * (ln >> 5);
            #pragma unroll
            for (int g = 0; g < 6; ++g)
                #pragma unroll
                for (int r = 0; r < 16; ++r) {
                    const int crow = rbase + (r & 3) + 8 * (r >> 2);
                    pb[((w2 * 6 + g) * 32 + crow) * 33 + ccol] = acc[g][r];
                }
        }
        __syncthreads();

        // ---------------- EW (fused) ----------------
        float lsum = 0.f;
        uint32_t pk[4];
        #pragma unroll
        for (int q = 0; q < 4; ++q) {
            const int dl = ec0 + q, d = ng * 32 + dl;
            float cg[6];
            #pragma unroll
            for (int g = 0; g < 6; ++g) {
                const int o0 = (g * 32 + er) * 33 + dl;
                const int o1 = ((6 + g) * 32 + er) * 33 + dl;
                cg[g] = part01[o0] + part01[o1] + part23[o0] + part23[o1];
            }
            float hnew = 0.f;
            if (d < DD) {
                float ir  = cg[0] + bih[d];
                float iz  = cg[1] + bih[DD + d];
                float inn = cg[2] + bih[2 * DD + d];
                float hr = bhh[d], hz = bhh[DD + d], hnn = bhh[2 * DD + d];
                float hp = 0.f;
                if (t > 0) {   // t=0: true h_prev = 0, gh half = bias only
                    hr += cg[3]; hz += cg[4]; hnn += cg[5];
                    hp = hout[(size_t)gb * DD + d];
                }
                float r = 1.0f / (1.0f + expf(-(ir + hr)));
                float z = 1.0f / (1.0f + expf(-(iz + hz)));
                float n = tanhf(inn + r * hnn);
                hnew = (1.0f - z) * n + z * hp;
                hout[(size_t)gb * DD + d] = hnew;   // block-owned: plain store
                lsum += hnew;
            }
            pk[q] = pack_hl(hnew);                  // pad dims -> 0
        }
        {
            uint32_t* Hn = (t & 1) ? Hp1 : Hp0;
            uint64_t q0 = ((uint64_t)pk[1] << 32) | pk[0];
            uint64_t q1 = ((uint64_t)pk[3] << 32) | pk[2];
            uint64_t* dst = (uint64_t*)(Hn + (size_t)gb * 512 + ng * 32 + ec0);
            __hip_atomic_store(dst,     q0, __ATOMIC_RELAXED, __HIP_MEMORY_SCOPE_AGENT);
            __hip_atomic_store(dst + 1, q1, __ATOMIC_RELAXED, __HIP_MEMORY_SCOPE_AGENT);
        }

        // ---------------- mean + counter barrier ----------------
        float v = lsum;
        #pragma unroll
        for (int off = 32; off > 0; off >>= 1) v += __shfl_down(v, off, 64);
        if (ln == 0) red[wv] = v;
        __syncthreads();
        if (tid == 0) {
            float s = red[0] + red[1] + red[2] + red[3];
            __hip_atomic_fetch_add(&slots[t], s, __ATOMIC_RELAXED, __HIP_MEMORY_SCOPE_AGENT);
            // release: waits vmcnt(0) -> all Hp stores visible before count
            __hip_atomic_fetch_add(cnt, 1u, __ATOMIC_RELEASE, __HIP_MEMORY_SCOPE_AGENT);
            const unsigned tgt = (unsigned)(t + 1) * NBLK;
            while (__hip_atomic_load(cnt, __ATOMIC_RELAXED, __HIP_MEMORY_SCOPE_AGENT) < tgt)
                __builtin_amdgcn_s_sleep(8);
            float st = __hip_atomic_load(&slots[t], __ATOMIC_RELAXED, __HIP_MEMORY_SCOPE_AGENT);
            dflag = (st > thr) ? 1 : 0;
        }
        __syncthreads();
        if (dflag) break;   // latch fired at step t: hout == h_t == s_fin
    }
}

extern "C" void kernel_launch(void* const* d_in, const int* in_sizes, int n_in,
                              void* d_out, int out_size, void* d_ws, size_t ws_size,
                              hipStream_t stream)
{
    const float* state = (const float*)d_in[0];
    const float* Wih   = (const float*)d_in[1];
    const float* Whh   = (const float*)d_in[2];
    const float* bih   = (const float*)d_in[3];
    const float* bhh   = (const float*)d_in[4];
    const float* bc    = (const float*)d_in[5];
    const int*   rec   = (const int*)d_in[6];

    char* ws = (char*)d_ws;
    unsigned* cnt   = (unsigned*)ws;                       // 4 B
    float*    slots = (float*)(ws + 256);                  // 64 floats
    uint32_t* Hp0   = (uint32_t*)(ws + 4096);              // 512x512 packed (1 MB)
    uint32_t* Hp1   = Hp0 + 512 * 512;
    f16*      Wp    = (f16*)(ws + 4096 + 2u * 512 * 512 * 4);  // 9.4 MB
    float*    out   = (float*)d_out;

    hipMemsetAsync(ws, 0, 1024, stream);   // cnt + slots
    // rec==0 robustness: output = state if no iteration runs
    hipMemcpyAsync(out, state, (size_t)NELEM * sizeof(float),
                   hipMemcpyDeviceToDevice, stream);

    conv_w<<<dim3(96 * KSTEPS * 64 / 256), 256, 0, stream>>>(Wih, Whh, Wp);

    gru_persist<<<dim3(NBLK), dim3(256), 0, stream>>>(
        state, Wp, Hp0, Hp1, bih, bhh, out, bc, rec, slots, cnt);
}